// Round 1
// baseline (491.043 us; speedup 1.0000x reference)
//
#include <hip/hip_runtime.h>
#include <hip/hip_bf16.h>

#define N 8192
#define HID 64
#define JC 8   // J-chunks per I-tile: grid = 128*JC blocks

typedef __attribute__((ext_vector_type(4))) float f32x4;
typedef __attribute__((ext_vector_type(8))) __bf16 bf16x8;

// ---------------- Kernel A: projection + L2 normalize -> bf16 ----------------
// h = elu(x @ W1^T + b1); z = h @ W2^T + b2; zhat = z / max(||z||, 1e-12)
// One wave per row; lane j computes output feature j. W1/W2 staged in LDS with
// stride-68 padding: dword addr lane*68+4q -> start bank 4*((lane+q)&7), same
// distribution as the measured-conflict-free b128 baseline (m134).
__global__ __launch_bounds__(256) void proj_kernel(
    const float* __restrict__ x1, const float* __restrict__ x2,
    const float* __restrict__ W1, const float* __restrict__ b1,
    const float* __restrict__ W2, const float* __restrict__ b2,
    __bf16* __restrict__ Z1h, __bf16* __restrict__ Z2h)
{
  __shared__ __align__(16) float w1s[64*68];
  __shared__ __align__(16) float w2s[64*68];
  __shared__ __align__(16) float xs[4][64];
  __shared__ __align__(16) float hs[4][64];

  const int tid  = threadIdx.x;
  const int lane = tid & 63;
  const int w    = tid >> 6;

  for (int idx = tid; idx < 64*64; idx += 256) {
    int j = idx >> 6, k = idx & 63;
    w1s[j*68+k] = W1[idx];
    w2s[j*68+k] = W2[idx];
  }
  __syncthreads();

  const float bias1 = b1[lane];
  const float bias2 = b2[lane];

  const int wave_global = blockIdx.x * 4 + w;   // 0..1023 with grid=256
  #pragma unroll 1
  for (int it = 0; it < 16; ++it) {
    int R = wave_global * 16 + it;              // 0..16383
    const float* src; __bf16* dst;
    if (R < N) { src = x1 + (size_t)R*HID;      dst = Z1h + (size_t)R*HID; }
    else       { src = x2 + (size_t)(R-N)*HID;  dst = Z2h + (size_t)(R-N)*HID; }

    float xv = src[lane];
    xs[w][lane] = xv;
    float acc = bias1;
    #pragma unroll
    for (int qq = 0; qq < 16; ++qq) {
      f32x4 xq = *(const f32x4*)&xs[w][qq*4];            // broadcast read
      f32x4 wq = *(const f32x4*)&w1s[lane*68 + qq*4];
      acc += xq.x*wq.x + xq.y*wq.y + xq.z*wq.z + xq.w*wq.w;
    }
    float h = acc > 0.f ? acc : expm1f(acc);             // ELU (alpha=1)
    hs[w][lane] = h;
    float acc2 = bias2;
    #pragma unroll
    for (int qq = 0; qq < 16; ++qq) {
      f32x4 hq = *(const f32x4*)&hs[w][qq*4];
      f32x4 wq = *(const f32x4*)&w2s[lane*68 + qq*4];
      acc2 += hq.x*wq.x + hq.y*wq.y + hq.z*wq.z + hq.w*wq.w;
    }
    float z = acc2;
    float ss = z*z;
    #pragma unroll
    for (int m = 1; m < 64; m <<= 1) ss += __shfl_xor(ss, m);
    float inv = 1.0f / fmaxf(sqrtf(ss), 1e-12f);
    dst[lane] = (__bf16)(z * inv);
  }
}

// ---------------- Kernel B: tiled exp-sim accumulation ----------------
// Per wave: 16 I-rows fixed (A-frags of Zhat1[I] and Zhat2[I] in registers),
// sweep J in 16-col steps. T1 = exp(Z1[I]Z2[J]^T/tau) feeds (rowsum1,num1);
// T2 = exp(Z2[I]Z1[J]^T/tau) feeds (rowsum2,num2); both share pos[I,J].
// MFMA 16x16x32 bf16: A/B frag: row = lane&15, k = (lane>>4)*8 + j (verified
// m120/m91); C/D: col = lane&15, row = (lane>>4)*4 + reg (verified m89/m91).
__global__ __launch_bounds__(256) void sim_kernel(
    const __bf16* __restrict__ Z1h, const __bf16* __restrict__ Z2h,
    const float* __restrict__ pos,
    float* __restrict__ rowsum1, float* __restrict__ num1,
    float* __restrict__ rowsum2, float* __restrict__ num2)
{
  const int tid  = threadIdx.x;
  const int lane = tid & 63;
  const int w    = tid >> 6;
  const int r16  = lane & 15;
  const int q    = lane >> 4;

  const int bi = blockIdx.x / JC;   // 0..127 I-tile
  const int jc = blockIdx.x % JC;
  const int i0 = bi*64 + w*16;

  const __bf16* z1r = Z1h + (size_t)(i0 + r16)*HID + q*8;
  const __bf16* z2r = Z2h + (size_t)(i0 + r16)*HID + q*8;
  bf16x8 a1lo = *(const bf16x8*)(z1r);
  bf16x8 a1hi = *(const bf16x8*)(z1r + 32);
  bf16x8 a2lo = *(const bf16x8*)(z2r);
  bf16x8 a2hi = *(const bf16x8*)(z2r + 32);

  float s1[4] = {0.f,0.f,0.f,0.f}, n1[4] = {0.f,0.f,0.f,0.f};
  float s2[4] = {0.f,0.f,0.f,0.f}, n2[4] = {0.f,0.f,0.f,0.f};

  const int jbeg = jc * (N/JC);
  const int jend = jbeg + (N/JC);
  const float Cexp = 1.8033688011112042f;  // 1/(TAU*ln2), TAU=0.8

  const float* pbase = pos + (size_t)(i0 + q*4)*N + r16;

  for (int j0 = jbeg; j0 < jend; j0 += 16) {
    const __bf16* zb2 = Z2h + (size_t)(j0 + r16)*HID + q*8;
    const __bf16* zb1 = Z1h + (size_t)(j0 + r16)*HID + q*8;
    bf16x8 b2lo = *(const bf16x8*)(zb2);
    bf16x8 b2hi = *(const bf16x8*)(zb2 + 32);
    bf16x8 b1lo = *(const bf16x8*)(zb1);
    bf16x8 b1hi = *(const bf16x8*)(zb1 + 32);

    const float* pp = pbase + j0;
    float p0 = pp[0];
    float p1 = pp[(size_t)N];
    float p2 = pp[(size_t)2*N];
    float p3 = pp[(size_t)3*N];

    f32x4 zero4 = {0.f,0.f,0.f,0.f};
    f32x4 d1 = __builtin_amdgcn_mfma_f32_16x16x32_bf16(a1lo, b2lo, zero4, 0,0,0);
    d1       = __builtin_amdgcn_mfma_f32_16x16x32_bf16(a1hi, b2hi, d1,    0,0,0);
    f32x4 d2 = __builtin_amdgcn_mfma_f32_16x16x32_bf16(a2lo, b1lo, zero4, 0,0,0);
    d2       = __builtin_amdgcn_mfma_f32_16x16x32_bf16(a2hi, b1hi, d2,    0,0,0);

    float pv[4] = {p0, p1, p2, p3};
    #pragma unroll
    for (int r = 0; r < 4; ++r) {
      float e1 = exp2f(d1[r] * Cexp);
      float e2 = exp2f(d2[r] * Cexp);
      s1[r] += e1; n1[r] += e1 * pv[r];
      s2[r] += e2; n2[r] += e2 * pv[r];
    }
  }

  // reduce across the 16 lanes of each quad (cols), leaving per-row sums
  #pragma unroll
  for (int r = 0; r < 4; ++r) {
    #pragma unroll
    for (int m = 1; m < 16; m <<= 1) {
      s1[r] += __shfl_xor(s1[r], m);
      n1[r] += __shfl_xor(n1[r], m);
      s2[r] += __shfl_xor(s2[r], m);
      n2[r] += __shfl_xor(n2[r], m);
    }
  }
  if (r16 == 0) {
    #pragma unroll
    for (int r = 0; r < 4; ++r) {
      int row = i0 + q*4 + r;
      atomicAdd(&rowsum1[row], s1[r]);
      atomicAdd(&num1[row],    n1[r]);
      atomicAdd(&rowsum2[row], s2[r]);
      atomicAdd(&num2[row],    n2[r]);
    }
  }
}

// ---------------- Kernel C: final loss reduction ----------------
__global__ __launch_bounds__(256) void loss_kernel(
    const float* __restrict__ rowsum1, const float* __restrict__ num1,
    const float* __restrict__ rowsum2, const float* __restrict__ num2,
    float* __restrict__ out)
{
  __shared__ float part[4];
  const int tid = threadIdx.x, lane = tid & 63, w = tid >> 6;
  float acc = 0.f;
  for (int i = tid; i < N; i += 256) {
    float sc = -logf(num1[i]/(rowsum1[i]+1e-8f) + 1e-8f);
    float mp = -logf(num2[i]/(rowsum2[i]+1e-8f) + 1e-8f);
    acc += 0.5f*sc + 0.5f*mp;   // LAMBDA = 0.5
  }
  #pragma unroll
  for (int m = 1; m < 64; m <<= 1) acc += __shfl_xor(acc, m);
  if (lane == 0) part[w] = acc;
  __syncthreads();
  if (tid == 0) out[0] = (part[0]+part[1]+part[2]+part[3]) * (1.0f/N);
}

extern "C" void kernel_launch(void* const* d_in, const int* in_sizes, int n_in,
                              void* d_out, int out_size, void* d_ws, size_t ws_size,
                              hipStream_t stream) {
  const float* x1  = (const float*)d_in[0];
  const float* x2  = (const float*)d_in[1];
  const float* W1  = (const float*)d_in[2];
  const float* b1  = (const float*)d_in[3];
  const float* W2  = (const float*)d_in[4];
  const float* b2  = (const float*)d_in[5];
  const float* pos = (const float*)d_in[6];

  char* ws = (char*)d_ws;
  __bf16* Z1h = (__bf16*)ws;
  __bf16* Z2h = (__bf16*)(ws + (size_t)N*HID*sizeof(__bf16));
  size_t zbytes = (size_t)2*N*HID*sizeof(__bf16);   // 2 MB
  float* rowsum1 = (float*)(ws + zbytes);
  float* num1    = rowsum1 + N;
  float* rowsum2 = num1 + N;
  float* num2    = rowsum2 + N;

  hipMemsetAsync(ws + zbytes, 0, (size_t)4*N*sizeof(float), stream);
  proj_kernel<<<256, 256, 0, stream>>>(x1, x2, W1, b1, W2, b2, Z1h, Z2h);
  sim_kernel<<<128*JC, 256, 0, stream>>>(Z1h, Z2h, pos, rowsum1, num1, rowsum2, num2);
  loss_kernel<<<1, 256, 0, stream>>>(rowsum1, num1, rowsum2, num2, (float*)d_out);
}

// Round 2
// 449.610 us; speedup vs baseline: 1.0922x; 1.0922x over previous
//
#include <hip/hip_runtime.h>
#include <hip/hip_bf16.h>

#define N 8192
#define HID 64
#define JC 16   // J-chunks per I-tile: grid = 128*JC blocks

typedef __attribute__((ext_vector_type(4))) float f32x4;
typedef __attribute__((ext_vector_type(8))) __bf16 bf16x8;

// ---------------- Kernel A: projection + L2 normalize -> bf16 ----------------
// h = elu(x @ W1^T + b1); z = h @ W2^T + b2; zhat = z / max(||z||, 1e-12)
// One wave per row-iteration; lane j = output feature j. W1/W2 in LDS with
// stride-68 padding (conflict-free f32x4 reads). 1024 blocks -> 4 rows/wave.
__global__ __launch_bounds__(256) void proj_kernel(
    const float* __restrict__ x1, const float* __restrict__ x2,
    const float* __restrict__ W1, const float* __restrict__ b1,
    const float* __restrict__ W2, const float* __restrict__ b2,
    __bf16* __restrict__ Z1h, __bf16* __restrict__ Z2h)
{
  __shared__ __align__(16) float w1s[64*68];
  __shared__ __align__(16) float w2s[64*68];
  __shared__ __align__(16) float xs[4][64];
  __shared__ __align__(16) float hs[4][64];

  const int tid  = threadIdx.x;
  const int lane = tid & 63;
  const int w    = tid >> 6;

  for (int idx = tid; idx < 64*64; idx += 256) {
    int j = idx >> 6, k = idx & 63;
    w1s[j*68+k] = W1[idx];
    w2s[j*68+k] = W2[idx];
  }
  __syncthreads();

  const float bias1 = b1[lane];
  const float bias2 = b2[lane];

  const int wave_global = blockIdx.x * 4 + w;   // 0..4095 with grid=1024
  #pragma unroll 1
  for (int it = 0; it < 4; ++it) {
    int R = wave_global * 4 + it;               // 0..16383
    const float* src; __bf16* dst;
    if (R < N) { src = x1 + (size_t)R*HID;      dst = Z1h + (size_t)R*HID; }
    else       { src = x2 + (size_t)(R-N)*HID;  dst = Z2h + (size_t)(R-N)*HID; }

    float xv = src[lane];
    xs[w][lane] = xv;
    float acc = bias1;
    #pragma unroll
    for (int qq = 0; qq < 16; ++qq) {
      f32x4 xq = *(const f32x4*)&xs[w][qq*4];            // broadcast read
      f32x4 wq = *(const f32x4*)&w1s[lane*68 + qq*4];
      acc += xq.x*wq.x + xq.y*wq.y + xq.z*wq.z + xq.w*wq.w;
    }
    float h = acc > 0.f ? acc : expm1f(acc);             // ELU (alpha=1)
    hs[w][lane] = h;
    float acc2 = bias2;
    #pragma unroll
    for (int qq = 0; qq < 16; ++qq) {
      f32x4 hq = *(const f32x4*)&hs[w][qq*4];
      f32x4 wq = *(const f32x4*)&w2s[lane*68 + qq*4];
      acc2 += hq.x*wq.x + hq.y*wq.y + hq.z*wq.z + hq.w*wq.w;
    }
    float z = acc2;
    float ss = z*z;
    #pragma unroll
    for (int m = 1; m < 64; m <<= 1) ss += __shfl_xor(ss, m);
    float inv = 1.0f / fmaxf(sqrtf(ss), 1e-12f);
    dst[lane] = (__bf16)(z * inv);
  }
}

// ---------------- Kernel B: tiled exp-sim accumulation ----------------
// Per wave: 16 I-rows fixed (A-frags in registers), sweep J in 32-col steps
// (2x16 MFMA tiles per iter -> 16 loads in flight). Both exp-sim matrices
// (T1 = exp(Z1 Z2^T/tau), T2 = exp(Z2 Z1^T/tau)) consume the same pos tile.
// MFMA 16x16x32 bf16 layouts verified in R1 (absmax 0).
__global__ __launch_bounds__(256, 6) void sim_kernel(
    const __bf16* __restrict__ Z1h, const __bf16* __restrict__ Z2h,
    const float* __restrict__ pos,
    float* __restrict__ rowsum1, float* __restrict__ num1,
    float* __restrict__ rowsum2, float* __restrict__ num2)
{
  const int tid  = threadIdx.x;
  const int lane = tid & 63;
  const int w    = tid >> 6;
  const int r16  = lane & 15;
  const int q    = lane >> 4;

  const int bi = blockIdx.x / JC;   // 0..127 I-tile
  const int jc = blockIdx.x % JC;
  const int i0 = bi*64 + w*16;

  const __bf16* z1r = Z1h + (size_t)(i0 + r16)*HID + q*8;
  const __bf16* z2r = Z2h + (size_t)(i0 + r16)*HID + q*8;
  bf16x8 a1lo = *(const bf16x8*)(z1r);
  bf16x8 a1hi = *(const bf16x8*)(z1r + 32);
  bf16x8 a2lo = *(const bf16x8*)(z2r);
  bf16x8 a2hi = *(const bf16x8*)(z2r + 32);

  float s1[4] = {0.f,0.f,0.f,0.f}, n1[4] = {0.f,0.f,0.f,0.f};
  float s2[4] = {0.f,0.f,0.f,0.f}, n2[4] = {0.f,0.f,0.f,0.f};

  const int jbeg = jc * (N/JC);
  const int jend = jbeg + (N/JC);
  const float Cexp = 1.8033688011112042f;  // 1/(TAU*ln2), TAU=0.8

  const float* pbase = pos + (size_t)(i0 + q*4)*N + r16;

  #pragma unroll 1
  for (int j0 = jbeg; j0 < jend; j0 += 32) {
    bf16x8 b2l[2], b2h[2], b1l[2], b1h[2];
    float pv[2][4];
    #pragma unroll
    for (int c = 0; c < 2; ++c) {
      const __bf16* zb2 = Z2h + (size_t)(j0 + c*16 + r16)*HID + q*8;
      const __bf16* zb1 = Z1h + (size_t)(j0 + c*16 + r16)*HID + q*8;
      b2l[c] = *(const bf16x8*)(zb2);
      b2h[c] = *(const bf16x8*)(zb2 + 32);
      b1l[c] = *(const bf16x8*)(zb1);
      b1h[c] = *(const bf16x8*)(zb1 + 32);
      const float* pp = pbase + j0 + c*16;
      pv[c][0] = pp[0];
      pv[c][1] = pp[(size_t)N];
      pv[c][2] = pp[(size_t)2*N];
      pv[c][3] = pp[(size_t)3*N];
    }
    #pragma unroll
    for (int c = 0; c < 2; ++c) {
      f32x4 zero4 = {0.f,0.f,0.f,0.f};
      f32x4 d1 = __builtin_amdgcn_mfma_f32_16x16x32_bf16(a1lo, b2l[c], zero4, 0,0,0);
      d1       = __builtin_amdgcn_mfma_f32_16x16x32_bf16(a1hi, b2h[c], d1,    0,0,0);
      f32x4 d2 = __builtin_amdgcn_mfma_f32_16x16x32_bf16(a2lo, b1l[c], zero4, 0,0,0);
      d2       = __builtin_amdgcn_mfma_f32_16x16x32_bf16(a2hi, b1h[c], d2,    0,0,0);
      #pragma unroll
      for (int r = 0; r < 4; ++r) {
        float e1 = exp2f(d1[r] * Cexp);
        float e2 = exp2f(d2[r] * Cexp);
        s1[r] += e1; n1[r] += e1 * pv[c][r];
        s2[r] += e2; n2[r] += e2 * pv[c][r];
      }
    }
  }

  // reduce across the 16 lanes of each quad (cols), leaving per-row sums
  #pragma unroll
  for (int r = 0; r < 4; ++r) {
    #pragma unroll
    for (int m = 1; m < 16; m <<= 1) {
      s1[r] += __shfl_xor(s1[r], m);
      n1[r] += __shfl_xor(n1[r], m);
      s2[r] += __shfl_xor(s2[r], m);
      n2[r] += __shfl_xor(n2[r], m);
    }
  }
  if (r16 == 0) {
    #pragma unroll
    for (int r = 0; r < 4; ++r) {
      int row = i0 + q*4 + r;
      atomicAdd(&rowsum1[row], s1[r]);
      atomicAdd(&num1[row],    n1[r]);
      atomicAdd(&rowsum2[row], s2[r]);
      atomicAdd(&num2[row],    n2[r]);
    }
  }
}

// ---------------- Kernel C: final loss reduction ----------------
__global__ __launch_bounds__(1024) void loss_kernel(
    const float* __restrict__ rowsum1, const float* __restrict__ num1,
    const float* __restrict__ rowsum2, const float* __restrict__ num2,
    float* __restrict__ out)
{
  __shared__ float part[16];
  const int tid = threadIdx.x, lane = tid & 63, w = tid >> 6;
  float acc = 0.f;
  for (int i = tid; i < N; i += 1024) {
    float sc = -logf(num1[i]/(rowsum1[i]+1e-8f) + 1e-8f);
    float mp = -logf(num2[i]/(rowsum2[i]+1e-8f) + 1e-8f);
    acc += 0.5f*sc + 0.5f*mp;   // LAMBDA = 0.5
  }
  #pragma unroll
  for (int m = 1; m < 64; m <<= 1) acc += __shfl_xor(acc, m);
  if (lane == 0) part[w] = acc;
  __syncthreads();
  if (tid == 0) {
    float t = 0.f;
    #pragma unroll
    for (int k = 0; k < 16; ++k) t += part[k];
    out[0] = t * (1.0f/N);
  }
}

extern "C" void kernel_launch(void* const* d_in, const int* in_sizes, int n_in,
                              void* d_out, int out_size, void* d_ws, size_t ws_size,
                              hipStream_t stream) {
  const float* x1  = (const float*)d_in[0];
  const float* x2  = (const float*)d_in[1];
  const float* W1  = (const float*)d_in[2];
  const float* b1  = (const float*)d_in[3];
  const float* W2  = (const float*)d_in[4];
  const float* b2  = (const float*)d_in[5];
  const float* pos = (const float*)d_in[6];

  char* ws = (char*)d_ws;
  __bf16* Z1h = (__bf16*)ws;
  __bf16* Z2h = (__bf16*)(ws + (size_t)N*HID*sizeof(__bf16));
  size_t zbytes = (size_t)2*N*HID*sizeof(__bf16);   // 2 MB
  float* rowsum1 = (float*)(ws + zbytes);
  float* num1    = rowsum1 + N;
  float* rowsum2 = num1 + N;
  float* num2    = rowsum2 + N;

  hipMemsetAsync(ws + zbytes, 0, (size_t)4*N*sizeof(float), stream);
  proj_kernel<<<1024, 256, 0, stream>>>(x1, x2, W1, b1, W2, b2, Z1h, Z2h);
  sim_kernel<<<128*JC, 256, 0, stream>>>(Z1h, Z2h, pos, rowsum1, num1, rowsum2, num2);
  loss_kernel<<<1, 1024, 0, stream>>>(rowsum1, num1, rowsum2, num2, (float*)d_out);
}